// Round 9
// baseline (37.068 us; speedup 1.0000x reference)
//
#include <hip/hip_runtime.h>

#define IMG 256
#define NB 64
#define NCH 8
#define NROWS (NB * IMG)   // 16384 (b,h) rows
#define PLANE (IMG * IMG)  // 65536

typedef float vf4 __attribute__((ext_vector_type(4)));
typedef float vf2 __attribute__((ext_vector_type(2)));

// floor(sqrt(x)) for 0 <= x <= 65535, exact via f32 sqrt + +/-1 correction
__device__ __forceinline__ int isqrt_i(int x) {
    int t = (int)__builtin_sqrtf((float)x);
    t -= (t * t > x);
    t += ((t + 1) * (t + 1) <= x);
    return t;
}

// Closed-form row interval count. mask(b,h,w) <=> (2w-255)^2 + (2h-255)^2 < s^2
// (exact integer equivalence with the reference's f32 sqrt comparison).
// cnt is even; interval is [lo, 255-lo] with lo = (255 - (cnt-1))/2.
__device__ __forceinline__ int row_count(int s, int h) {
    int ky = 2 * h - 255;
    int rem = s * s - ky * ky;
    if (rem < 2) return 0;             // need kx^2 < rem with kx odd >= 1
    int t = isqrt_i(rem - 1);          // largest t with t^2 < rem
    int kx_max = (t & 1) ? t : t - 1;  // kx = 255-2w is odd
    return kx_max + 1;
}

// Setup: one block, 1024 threads. rowinfo[row] = {n0 (global prefix), lo|cnt<<16}.
__global__ void setup_kernel(const int* __restrict__ sizes,
                             int2* __restrict__ rowinfo,
                             float* __restrict__ out, int out_size) {
    __shared__ int tot[NB];
    __shared__ int ibase[NB];
    int t = threadIdx.x;          // 0..1023
    int lane = t & 63;
    int b = t >> 4;
    int h0 = (t & 15) * 16;
    int s = sizes[b];

    int c[16];
    int chunksum = 0;
    #pragma unroll
    for (int k = 0; k < 16; ++k) { c[k] = row_count(s, h0 + k); chunksum += c[k]; }

    // segmented inclusive scan within 16-lane groups (one image per group)
    int v = chunksum;
    #pragma unroll
    for (int d = 1; d < 16; d <<= 1) {
        int u = __shfl_up(v, d);
        if ((lane & 15) >= d) v += u;
    }
    if ((t & 15) == 15) tot[b] = v;   // image total
    __syncthreads();
    if (t < NB) {
        int a = tot[t];
        int iv = a;
        #pragma unroll
        for (int d = 1; d < NB; d <<= 1) {
            int u = __shfl_up(iv, d);
            if (t >= d) iv += u;
        }
        ibase[t] = iv - a;            // exclusive image base
    }
    __syncthreads();

    int n0 = ibase[b] + (v - chunksum);   // global exclusive prefix
    #pragma unroll
    for (int k = 0; k < 16; ++k) {
        int cnt = c[k];
        int lo = (cnt > 0) ? ((255 - (cnt - 1)) >> 1) : 0;
        rowinfo[b * IMG + h0 + k] = make_int2(n0, lo | (cnt << 16));
        n0 += cnt;
    }
    if (t == 0) out[out_size - 1] = (float)NB;  // batch_size = 64
}

// Scatter: one block per row (XCD-swizzled so each XCD owns a contiguous
// 2048-row slab of input and output), thread = w. Prologue = one uniform
// 8B rowinfo load; then 8 coalesced scalar loads, 2x vf4 + vf2 + dword stores.
__global__ void __launch_bounds__(256) scatter_rows(
        const float* __restrict__ batch,
        const int2* __restrict__ rowinfo,
        float* __restrict__ out, int N) {
    // bijective XCD swizzle: 16384 rows = 8 XCDs x 2048 contiguous rows
    int row = (blockIdx.x & 7) * 2048 + (blockIdx.x >> 3);
    int2 ri = rowinfo[row];           // wave-uniform -> s_load
    int cnt = ri.y >> 16;
    if (cnt == 0) return;             // uniform exit (~38% of rows)
    int lo = ri.y & 0xffff;
    int t = threadIdx.x;
    if (t < lo || t >= lo + cnt) return;

    int b = row >> 8;
    int h = row & 255;
    int n = ri.x + (t - lo);

    const float* bp = batch + (size_t)b * NCH * PLANE + h * IMG + t;
    float c0 = bp[0 * PLANE], c1 = bp[1 * PLANE], c2 = bp[2 * PLANE],
          c3 = bp[3 * PLANE], c4 = bp[4 * PLANE], c5 = bp[5 * PLANE],
          c6 = bp[6 * PLANE], c7 = bp[7 * PLANE];

    vf4 t0, t1;
    t0.x = c0; t0.y = c1; t0.z = c2; t0.w = c3;
    t1.x = c4; t1.y = c5; t1.z = c6; t1.w = c7;
    *(vf4*)(out + (size_t)n * 8) = t0;
    *(vf4*)(out + (size_t)n * 8 + 4) = t1;

    vf2 p; p.x = (float)h; p.y = (float)t;
    *(vf2*)(out + (size_t)N * 8 + (size_t)n * 2) = p;

    out[(size_t)N * 10 + n] = (float)b;
}

extern "C" void kernel_launch(void* const* d_in, const int* in_sizes, int n_in,
                              void* d_out, int out_size, void* d_ws, size_t ws_size,
                              hipStream_t stream) {
    const float* batch = (const float*)d_in[0];
    const int* sizes = (const int*)d_in[1];
    float* out = (float*)d_out;

    // out layout: tex [N*8] | pts [N*2] | imgid [N] | batch_size [1]
    int N = (out_size - 1) / 11;

    int2* rowinfo = (int2*)d_ws;   // 16384 * 8B = 128 KB

    setup_kernel<<<1, 1024, 0, stream>>>(sizes, rowinfo, out, out_size);
    scatter_rows<<<NROWS, 256, 0, stream>>>(batch, rowinfo, out, N);
}

// Round 10
// 30.000 us; speedup vs baseline: 1.2356x; 1.2356x over previous
//
#include <hip/hip_runtime.h>

#define IMG 256
#define NB 64
#define NCH 8
#define NROWS (NB * IMG)   // 16384 (b,h) rows
#define PLANE (IMG * IMG)  // 65536

typedef float vf4 __attribute__((ext_vector_type(4)));
typedef float vf2 __attribute__((ext_vector_type(2)));

// floor(sqrt(x)) for 0 <= x <= 65535, exact via f32 sqrt + +/-1 correction
__device__ __forceinline__ int isqrt_i(int x) {
    int t = (int)__builtin_sqrtf((float)x);
    t -= (t * t > x);
    t += ((t + 1) * (t + 1) <= x);
    return t;
}

// Closed-form row interval count. mask(b,h,w) <=> (2w-255)^2 + (2h-255)^2 < s^2
// (exact integer equivalence with the reference's f32 sqrt comparison).
// cnt is even; interval is [lo, 255-lo] with lo = (255 - (cnt-1))/2.
__device__ __forceinline__ int row_count(int s, int h) {
    int ky = 2 * h - 255;
    int rem = s * s - ky * ky;
    if (rem < 2) return 0;             // need kx^2 < rem with kx odd >= 1
    int t = isqrt_i(rem - 1);          // largest t with t^2 < rem
    int kx_max = (t & 1) ? t : t - 1;  // kx = 255-2w is odd
    return kx_max + 1;
}

// Setup: one block, 1024 threads. Only image_base[64] + trailing batch_size.
__global__ void setup_kernel(const int* __restrict__ sizes,
                             int* __restrict__ image_base,
                             float* __restrict__ out, int out_size) {
    __shared__ int tot[NB];
    int t = threadIdx.x;          // 0..1023
    int b = t >> 4;
    int h0 = (t & 15) * 16;
    int s = sizes[b];
    int sum = 0;
    #pragma unroll
    for (int k = 0; k < 16; ++k) sum += row_count(s, h0 + k);
    // reduce 16 threads -> image total via shuffle (threads of one image are
    // consecutive lanes within a wave)
    #pragma unroll
    for (int d = 1; d < 16; d <<= 1) sum += __shfl_down(sum, d);
    if ((t & 15) == 0) tot[b] = sum;
    __syncthreads();
    if (t < NB) {
        int a = tot[t];
        int iv = a;
        #pragma unroll
        for (int d = 1; d < NB; d <<= 1) {
            int u = __shfl_up(iv, d);
            if (t >= d) iv += u;
        }
        image_base[t] = iv - a;   // exclusive image base
    }
    if (t == 0) out[out_size - 1] = (float)NB;  // batch_size = 64
}

// Scatter: one block per row, thread = w. Reads staged through LDS:
// cooperative vf4 loads (2 per thread, 1KB/wave-instr), transpose in LDS
// (stride-9 pad), then R3's proven dense store pattern.
__global__ void __launch_bounds__(256) scatter_rows(
        const float* __restrict__ batch,
        const int* __restrict__ sizes,
        const int* __restrict__ image_base,
        float* __restrict__ out, int N) {
    int row = blockIdx.x;
    int b = row >> 8;
    int h = row & 255;
    int t = threadIdx.x;
    int s = sizes[b];                 // uniform
    int cnt = row_count(s, h);        // uniform
    if (cnt == 0) return;             // uniform exit (~38% of rows)
    int lo = (255 - (cnt - 1)) >> 1;
    int hi = lo + cnt;
    int lo4 = lo & ~3;

    // Phase A: issue cooperative vf4 loads early (latency hides under prefix)
    int c = t >> 5;                   // channel 0..7
    int l32 = t & 31;
    const float* cp = batch + (size_t)b * NCH * PLANE + (size_t)c * PLANE + h * IMG;
    int px0 = lo4 + l32 * 4;
    int px1 = lo4 + (32 + l32) * 4;
    bool pa = px0 < hi, pb = px1 < hi;
    vf4 va, vb;
    if (pa) va = *(const vf4*)(cp + px0);
    if (pb) vb = *(const vf4*)(cp + px1);

    // prefix: sum_{h'<h} row_count(s,h') via per-thread eval + block reduce
    int cc = (t < h) ? row_count(s, t) : 0;
    #pragma unroll
    for (int o = 32; o; o >>= 1) cc += __shfl_down(cc, o);
    __shared__ int wsum[4];
    __shared__ int s_n0;
    if ((t & 63) == 0) wsum[t >> 6] = cc;

    // LDS transpose: lds[px*9 + c] (pad 9 -> 4-way write conflict, reads ~free)
    __shared__ float lds[IMG * 9];
    if (pa) {
        #pragma unroll
        for (int k = 0; k < 4; ++k) lds[(px0 + k) * 9 + c] = va[k];
    }
    if (pb) {
        #pragma unroll
        for (int k = 0; k < 4; ++k) lds[(px1 + k) * 9 + c] = vb[k];
    }
    __syncthreads();
    if (t == 0) s_n0 = image_base[b] + wsum[0] + wsum[1] + wsum[2] + wsum[3];
    __syncthreads();

    // Phase B: thread = point; dense stores (R3's proven pattern)
    int w = t;
    if (w < lo || w >= hi) return;
    int n = s_n0 + (w - lo);

    vf4 t0, t1;
    t0.x = lds[w * 9 + 0]; t0.y = lds[w * 9 + 1];
    t0.z = lds[w * 9 + 2]; t0.w = lds[w * 9 + 3];
    t1.x = lds[w * 9 + 4]; t1.y = lds[w * 9 + 5];
    t1.z = lds[w * 9 + 6]; t1.w = lds[w * 9 + 7];
    *(vf4*)(out + (size_t)n * 8) = t0;
    *(vf4*)(out + (size_t)n * 8 + 4) = t1;

    vf2 p; p.x = (float)h; p.y = (float)w;
    *(vf2*)(out + (size_t)N * 8 + (size_t)n * 2) = p;

    out[(size_t)N * 10 + n] = (float)b;
}

extern "C" void kernel_launch(void* const* d_in, const int* in_sizes, int n_in,
                              void* d_out, int out_size, void* d_ws, size_t ws_size,
                              hipStream_t stream) {
    const float* batch = (const float*)d_in[0];
    const int* sizes = (const int*)d_in[1];
    float* out = (float*)d_out;

    // out layout: tex [N*8] | pts [N*2] | imgid [N] | batch_size [1]
    int N = (out_size - 1) / 11;

    int* image_base = (int*)d_ws;  // 64 ints

    setup_kernel<<<1, 1024, 0, stream>>>(sizes, image_base, out, out_size);
    scatter_rows<<<NROWS, 256, 0, stream>>>(batch, sizes, image_base, out, N);
}

// Round 11
// 24.487 us; speedup vs baseline: 1.5138x; 1.2251x over previous
//
#include <hip/hip_runtime.h>
#include <math.h>

#define IMG 256
#define NB 64
#define NCH 8
#define NROWS (NB * IMG)   // 16384 (b,h) rows
#define PLANE (IMG * IMG)  // 65536

typedef float vf4 __attribute__((ext_vector_type(4)));
typedef float vf2 __attribute__((ext_vector_type(2)));

// Area table for s in [64,256], passed by value (kernarg, ~772B < 1KB limit).
struct TabArg { int a[193]; };

// ---------- device helpers ----------

// floor(sqrt(x)) for 0 <= x <= 65535, exact via f32 sqrt + +/-1 correction
__device__ __forceinline__ int isqrt_i(int x) {
    int t = (int)__builtin_sqrtf((float)x);
    t -= (t * t > x);
    t += ((t + 1) * (t + 1) <= x);
    return t;
}

// Closed-form row interval count. mask(b,h,w) <=> (2w-255)^2 + (2h-255)^2 < s^2
// (exact integer equivalence with the reference's f32 sqrt comparison).
// cnt is even; interval is [lo, 255-lo] with lo = (255 - (cnt-1))/2.
__device__ __forceinline__ int row_count(int s, int h) {
    int ky = 2 * h - 255;
    int rem = s * s - ky * ky;
    if (rem < 2) return 0;             // need kx^2 < rem with kx odd >= 1
    int t = isqrt_i(rem - 1);          // largest t with t^2 < rem
    int kx_max = (t & 1) ? t : t - 1;  // kx = 255-2w is odd
    return kx_max + 1;
}

// ---------- single fused kernel ----------
// One block per (b,h) row, thread = w. No LDS, no barriers, no setup kernel.
// Global offset n0 = [wave-redundant] sum over lanes L of
//   (L < b ? area_tab[sizes[L]] : 0)  +  sum_k (L+64k < h ? row_count(s,L+64k) : 0)
// reduced across the wave. Channel loads are issued before the reduce so their
// latency hides under it.
__global__ void __launch_bounds__(256) fused_scatter(
        const float* __restrict__ batch,
        const int* __restrict__ sizes,
        float* __restrict__ out, int N, int out_size, TabArg tab) {
    int row = blockIdx.x;
    int t = threadIdx.x;
    if (row == 0 && t == 0) out[out_size - 1] = (float)NB;  // batch_size

    int b = row >> 8;
    int h = row & 255;
    int s = sizes[b];                 // wave-uniform -> scalar load, L1-hot
    int cnt = row_count(s, h);        // uniform
    if (cnt == 0) return;             // uniform exit (~38% of rows)
    int lo = (255 - (cnt - 1)) >> 1;
    int hi = lo + cnt;
    bool act = (t >= lo) & (t < hi);

    // issue the 8 channel loads immediately (predicated, stay in flight)
    const float* bp = batch + (size_t)b * NCH * PLANE + h * IMG + t;
    float c0, c1, c2, c3, c4, c5, c6, c7;
    if (act) {
        c0 = bp[0 * PLANE]; c1 = bp[1 * PLANE]; c2 = bp[2 * PLANE];
        c3 = bp[3 * PLANE]; c4 = bp[4 * PLANE]; c5 = bp[5 * PLANE];
        c6 = bp[6 * PLANE]; c7 = bp[7 * PLANE];
    }

    // combined prefix (redundant per wave; no LDS, no barrier)
    int L = t & 63;
    int v = (L < b) ? tab.a[sizes[L] - 64] : 0;   // cross-image base part
    #pragma unroll
    for (int k = 0; k < 4; ++k) {
        int hp = L + k * 64;
        v += (hp < h) ? row_count(s, hp) : 0;      // in-image prefix part
    }
    #pragma unroll
    for (int o = 32; o; o >>= 1) v += __shfl_down(v, o);
    int n0 = __shfl(v, 0);                          // broadcast wave-sum

    if (!act) return;
    int n = n0 + (t - lo);

    vf4 t0, t1;
    t0.x = c0; t0.y = c1; t0.z = c2; t0.w = c3;
    t1.x = c4; t1.y = c5; t1.z = c6; t1.w = c7;
    *(vf4*)(out + (size_t)n * 8) = t0;              // 32B-aligned
    *(vf4*)(out + (size_t)n * 8 + 4) = t1;

    vf2 p; p.x = (float)h; p.y = (float)t;
    *(vf2*)(out + (size_t)N * 8 + (size_t)n * 2) = p;

    out[(size_t)N * 10 + n] = (float)b;
}

// ---------- host ----------

static int h_isqrt(int x) {
    int t = (int)sqrt((double)x);
    while (t * t > x) --t;
    while ((t + 1) * (t + 1) <= x) ++t;
    return t;
}

static int h_row_count(int s, int h) {
    int ky = 2 * h - 255;
    int rem = s * s - ky * ky;
    if (rem < 2) return 0;
    int t = h_isqrt(rem - 1);
    int kx_max = (t & 1) ? t : t - 1;
    return kx_max + 1;
}

extern "C" void kernel_launch(void* const* d_in, const int* in_sizes, int n_in,
                              void* d_out, int out_size, void* d_ws, size_t ws_size,
                              hipStream_t stream) {
    const float* batch = (const float*)d_in[0];
    const int* sizes = (const int*)d_in[1];
    float* out = (float*)d_out;

    // out layout: tex [N*8] | pts [N*2] | imgid [N] | batch_size [1]
    int N = (out_size - 1) / 11;

    // pure function of s: area(s) = sum_h row_count(s,h); computed host-side
    // (capture/correctness path only -- not in the timed replay)
    TabArg tab;
    for (int s = 64; s <= 256; ++s) {
        int a = 0;
        for (int h = 0; h < 128; ++h) a += h_row_count(s, h);
        tab.a[s - 64] = 2 * a;   // h-symmetry: row_count(s,h) == row_count(s,255-h)
    }

    fused_scatter<<<NROWS, 256, 0, stream>>>(batch, sizes, out, N, out_size, tab);
}